// Round 1
// baseline (965.086 us; speedup 1.0000x reference)
//
#include <hip/hip_runtime.h>

// Broadcast a float from lane l (wave-uniform l) via v_readlane — VALU pipe,
// NOT ds_bpermute (keeps the per-CU LDS pipe free).
__device__ __forceinline__ float rdlane(float v, int l) {
    return __int_as_float(__builtin_amdgcn_readlane(__float_as_int(v), l));
}

// One wave = one 64x64 matrix. Thread j owns column j in registers A[0..63].
// Block = 128 threads: wave 0 -> spin-up matrix, wave 1 -> spin-dn matrix.
__global__ __launch_bounds__(128) void slater_logdet_kernel(
        const float* __restrict__ rs, const float* __restrict__ log_alpha_p,
        float* __restrict__ out) {
    const int b    = blockIdx.x;
    const int tid  = threadIdx.x;
    const int wave = tid >> 6;   // 0 = up, 1 = dn
    const int lane = tid & 63;

    const float Lbox = 10.0f;
    const float PI_F = 3.14159265358979323846f;

    float alpha = __expf(log_alpha_p[0]);
    alpha = fminf(fmaxf(alpha, 0.5f / (Lbox * Lbox)), 200.0f / (Lbox * Lbox));

    // electron position for this lane (row index of the matrix)
    const float* rp = rs + (size_t)b * 384 + (size_t)(wave * 64 + lane) * 3;
    float x = rp[0], y = rp[1], z = rp[2];

    // electron angles theta = pi*x/L: 6 transcendentals total per lane
    float sx, cx, sy, cy, sz, cz;
    __sincosf(x * (PI_F / Lbox), &sx, &cx);
    __sincosf(y * (PI_F / Lbox), &sy, &cy);
    __sincosf(z * (PI_F / Lbox), &sz, &cz);

    // center phases for column j = lane: c = 2.5*m (+1.25 for dn)
    // phi = pi*c/L = (pi/4)*(m + 0.5*spin)
    const int mx = (lane >> 4) & 3, my = (lane >> 2) & 3, mz = lane & 3;
    const float off = wave ? 0.5f : 0.0f;
    float spx, cpx, spy, cpy, spz, cpz;
    __sincosf((PI_F * 0.25f) * ((float)mx + off), &spx, &cpx);
    __sincosf((PI_F * 0.25f) * ((float)my + off), &spy, &cpy);
    __sincosf((PI_F * 0.25f) * ((float)mz + off), &spz, &cpz);

    // Build column: A[i] = exp(-alpha * sum_axis ((L/pi) sin(pi(dr)/L))^2)
    // sin(theta_i - phi_j) = sin(theta_i)cos(phi_j) - cos(theta_i)sin(phi_j)
    const float LPI = Lbox / PI_F;
    float A[64];
#pragma unroll
    for (int i = 0; i < 64; ++i) {
        float sxi = rdlane(sx, i), cxi = rdlane(cx, i);
        float syi = rdlane(sy, i), cyi = rdlane(cy, i);
        float szi = rdlane(sz, i), czi = rdlane(cz, i);
        float dx = LPI * (sxi * cpx - cxi * spx);
        float dy = LPI * (syi * cpy - cyi * spy);
        float dz = LPI * (szi * cpz - czi * spz);
        float r2 = dx * dx + dy * dy + dz * dz;
        A[i] = __expf(-alpha * r2);
    }

    // LU with partial pivoting, column-owner layout.
    // Rows i < k are dead (never read again): blocked k-loop statically skips
    // rows below the 16-row block base. Dead-row updates are garbage but
    // provably unread (argmax filters i>=k; broadcasts read only row k).
    float logdet = 0.0f;
#pragma unroll
    for (int bk = 0; bk < 4; ++bk) {
        const int base = bk * 16;
#pragma unroll 1
        for (int kk = 0; kk < 16; ++kk) {
            const int k = base + kk;
            // Pass 1: broadcast column k (uniform -> SGPRs), argmax |.| over
            // live rows, and gather old A[k] (ck) / col[k] (colk).
            float col[64];
            float best = -1.0f, pv = 1.0f, ck = 0.0f, colk = 1.0f;
            int p = k;
#pragma unroll
            for (int i = base; i < 64; ++i) {
                col[i] = rdlane(A[i], k);
                float ab = fabsf(col[i]);
                bool better = (i >= k) & (ab > best);
                best = better ? ab : best;
                pv   = better ? col[i] : pv;
                p    = better ? i : p;
                bool isk = (i == k);
                ck   = isk ? A[i]   : ck;
                colk = isk ? col[i] : colk;
            }
            // Pass 2: gather this thread's element of pivot row p.
            float cp = 0.0f;
#pragma unroll
            for (int i = base; i < 64; ++i) {
                cp = (i == p) ? A[i] : cp;
            }
            const float inv = 1.0f / pv;
            logdet += __logf(fabsf(pv));
            // Pass 3: implicit row-swap + rank-1 update.
            // new row k (pivot row) = old row p -> becomes U row, then dead.
            // new row p = old row k, updated with multiplier colk/pivot.
#pragma unroll
            for (int i = base; i < 64; ++i) {
                bool isp  = (i == p);
                float nc  = isp ? colk : col[i];  // column-k value after swap
                float m   = nc * inv;             // uniform multiplier
                float src = isp ? ck : A[i];      // row value after swap
                A[i] = __builtin_fmaf(-m, cp, src);
            }
        }
    }

    // logdet is lane-uniform. Combine the two spins.
    __shared__ float partial[2];
    if (lane == 0) partial[wave] = logdet;
    __syncthreads();
    if (tid == 0) out[b] = partial[0] + partial[1];
}

extern "C" void kernel_launch(void* const* d_in, const int* in_sizes, int n_in,
                              void* d_out, int out_size, void* d_ws, size_t ws_size,
                              hipStream_t stream) {
    const float* rs = (const float*)d_in[0];
    const float* la = (const float*)d_in[1];
    float* out      = (float*)d_out;
    // out_size == BATCH == 8192 blocks, 128 threads (2 waves: up, dn)
    slater_logdet_kernel<<<out_size, 128, 0, stream>>>(rs, la, out);
}

// Round 2
// 304.794 us; speedup vs baseline: 3.1664x; 3.1664x over previous
//
#include <hip/hip_runtime.h>

// Broadcast a float from lane l via v_readlane (VALU pipe, uniform result).
__device__ __forceinline__ float rdlane(float v, int l) {
    return __int_as_float(__builtin_amdgcn_readlane(__float_as_int(v), l));
}

// max(x, dpp_shuffle(x)) — one butterfly step of a 64-lane max reduction.
template <int CTRL>
__device__ __forceinline__ float dpp_max_step(float x) {
    int t = __builtin_amdgcn_update_dpp(0, __float_as_int(x), CTRL, 0xF, 0xF, true);
    return fmaxf(x, __int_as_float(t));
}

// Full 64-lane max; result valid in lane 63 (invalid DPP lanes inject 0.0,
// harmless here because the max is an abs-value, always >= 0).
__device__ __forceinline__ float wave_max_to_lane63(float x) {
    x = dpp_max_step<0xB1>(x);   // quad_perm [1,0,3,2]  (xor 1)
    x = dpp_max_step<0x4E>(x);   // quad_perm [2,3,0,1]  (xor 2)
    x = dpp_max_step<0x141>(x);  // row_half_mirror      (xor within 8)
    x = dpp_max_step<0x140>(x);  // row_mirror           (xor within 16)
    x = dpp_max_step<0x142>(x);  // row_bcast15          (16 -> 32)
    x = dpp_max_step<0x143>(x);  // row_bcast31          (32 -> 64)
    return x;                    // lane 63 holds the global max
}

// One wave = one 64x64 matrix, lane i owns ROW i in registers A[0..63].
// Block = 128 threads: wave 0 -> spin-up matrix, wave 1 -> spin-dn matrix.
__global__ __launch_bounds__(128) void slater_logdet_kernel(
        const float* __restrict__ rs, const float* __restrict__ log_alpha_p,
        float* __restrict__ out) {
    const int b    = blockIdx.x;
    const int tid  = threadIdx.x;
    const int wave = tid >> 6;   // 0 = up, 1 = dn
    const int lane = tid & 63;

    const float Lbox = 10.0f;
    const float PI_F = 3.14159265358979323846f;

    float alpha = __expf(log_alpha_p[0]);
    alpha = fminf(fmaxf(alpha, 0.5f / (Lbox * Lbox)), 200.0f / (Lbox * Lbox));

    // Electron position for this lane (row index = electron index).
    const float* rp = rs + (size_t)b * 384 + (size_t)(wave * 64 + lane) * 3;
    float x = rp[0], y = rp[1], z = rp[2];

    float sx, cx, sy, cy, sz, cz;
    __sincosf(x * (PI_F / Lbox), &sx, &cx);
    __sincosf(y * (PI_F / Lbox), &sy, &cy);
    __sincosf(z * (PI_F / Lbox), &sz, &cz);

    // Separable build: Phi[i][j] = ex[mx]*ey[my]*ez[mz], j = mx*16+my*4+mz.
    // Only 12 exps + ~80 muls per lane (vs 64 exps in the column layout).
    const float off = wave ? 0.5f : 0.0f;
    const float LPI = Lbox / PI_F;
    float ex[4], ey[4], ez[4];
#pragma unroll
    for (int m = 0; m < 4; ++m) {
        float sp, cp;
        __sincosf((PI_F * 0.25f) * ((float)m + off), &sp, &cp);
        float dx = LPI * (sx * cp - cx * sp);
        float dy = LPI * (sy * cp - cy * sp);
        float dz = LPI * (sz * cp - cz * sp);
        ex[m] = __expf(-alpha * dx * dx);
        ey[m] = __expf(-alpha * dy * dy);
        ez[m] = __expf(-alpha * dz * dz);
    }
    float exy[16];
#pragma unroll
    for (int q = 0; q < 16; ++q) exy[q] = ex[q >> 2] * ey[q & 3];
    float A[64];
#pragma unroll
    for (int j = 0; j < 64; ++j) A[j] = exy[j >> 2] * ez[j & 3];

    // LU with partial pivoting, row-owner layout, NO physical row swap:
    // pivot rows stay in their lane; flag = -inf marks them dead so the
    // argmax never selects them again. det sign is irrelevant (log|det|).
    float flag   = 0.0f;   // 0 while alive, -inf once used as pivot row
    float logdet = 0.0f;
    const int lane_v = lane;
#pragma unroll
    for (int k = 0; k < 64; ++k) {
        // key = |A[k]| for alive rows, -inf for dead rows (one v_add w/ |mod|)
        float key  = fabsf(A[k]) + flag;
        float gmax = rdlane(wave_max_to_lane63(key), 63);
        unsigned long long ball = __ballot(key == gmax);
        int p = (int)(__ffsll(ball) - 1);          // pivot row's physical lane

        float pv  = rdlane(A[k], p);
        float inv = __builtin_amdgcn_rcpf(pv);
        inv = inv * (2.0f - pv * inv);             // 1 Newton step (~0.5 ulp)
        logdet += __logf(fabsf(pv));

        // Mark pivot row dead for future argmaxes.
        flag = (lane_v == p) ? -__builtin_huge_valf() : flag;

        // One multiplier per lane in a single op; lane p gets m~=1 and
        // self-annihilates (row never read again), dead lanes have A[k]=~0.
        float m = A[k] * inv;
#pragma unroll
        for (int j = k + 1; j < 64; ++j) {
            float s = rdlane(A[j], p);             // pivot-row elem -> SGPR
            A[j] = __builtin_fmaf(-m, s, A[j]);    // all 64 rows at once
        }
    }

    // logdet is lane-uniform. Combine the two spins.
    __shared__ float partial[2];
    if (lane == 0) partial[wave] = logdet;
    __syncthreads();
    if (tid == 0) out[b] = partial[0] + partial[1];
}

extern "C" void kernel_launch(void* const* d_in, const int* in_sizes, int n_in,
                              void* d_out, int out_size, void* d_ws, size_t ws_size,
                              hipStream_t stream) {
    const float* rs = (const float*)d_in[0];
    const float* la = (const float*)d_in[1];
    float* out      = (float*)d_out;
    slater_logdet_kernel<<<out_size, 128, 0, stream>>>(rs, la, out);
}